// Round 5
// baseline (310.737 us; speedup 1.0000x reference)
//
#include <hip/hip_runtime.h>
#include <hip/hip_bf16.h>

#define T_TOK 8192
#define DH    1024
#define NE    8
#define TK    4

typedef unsigned short u16;
typedef __bf16 bf16x8 __attribute__((ext_vector_type(8)));
typedef float  f32x4  __attribute__((ext_vector_type(4)));

__device__ __forceinline__ u16 f2b(float f) {
    union { float f; unsigned u; } v; v.f = f;
    unsigned u = v.u;
    u += 0x7FFFu + ((u >> 16) & 1u);   // round-to-nearest-even
    return (u16)(u >> 16);
}
__device__ __forceinline__ float b2f(u16 h) {
    union { unsigned u; float f; } v; v.u = ((unsigned)h) << 16;
    return v.f;
}
// async global->LDS, 16B per lane; LDS dest = wave-uniform base + lane*16 (linear!)
// NOTE: offset arg must be a frontend literal (R4 compile fail) -> fold offsets into g.
__device__ __forceinline__ void glds16(const u16* g, u16* l) {
    __builtin_amdgcn_global_load_lds((const __attribute__((address_space(1))) void*)g,
                                     (__attribute__((address_space(3))) void*)l, 16, 0, 0);
}

#define FENCE() asm volatile("" ::: "memory")
#define SBAR()  do { FENCE(); __builtin_amdgcn_s_barrier(); FENCE(); } while (0)
// rule 18: hipcc can hoist reg-only MFMA past an inline-asm lgkmcnt; fence with sched_barrier(0)
#define WAITLGKM0() do { asm volatile("s_waitcnt lgkmcnt(0)" ::: "memory"); \
                         __builtin_amdgcn_sched_barrier(0); } while (0)
#define WAITVM(n) asm volatile("s_waitcnt vmcnt(" #n ")" ::: "memory")

// ---------------- fused prep: cast W (blocks 0..2047) + router (blocks 2048..4095) ----------------
__global__ __launch_bounds__(256) void prep_kernel(
    const float* __restrict__ W, u16* __restrict__ wbt,
    const float* __restrict__ x, const float* __restrict__ Wg, const float* __restrict__ bg,
    u16* __restrict__ xb,
    int* __restrict__ bucket_tok, float* __restrict__ bucket_w,
    int* __restrict__ tk_e, float* __restrict__ tk_w,
    int* __restrict__ cnt, float* __restrict__ probsum)
{
    __shared__ float tile[64][65];
    __shared__ int   lcnt[NE];
    __shared__ float lprob[NE];
    __shared__ int   gbase[NE];

    if (blockIdx.x < 2048) {
        // ------- cast W -> bf16, transposed to [e][f][d]; 64x64 tile -------
        const unsigned u = blockIdx.x;
        const int f0 = (u & 15) * 64;
        const int d0 = ((u >> 4) & 15) * 64;
        const int e  = u >> 8;
        const int r  = threadIdx.x >> 4;          // 0..15
        const int c4 = (threadIdx.x & 15) * 4;    // 0,4,...,60
        const float* src = W + ((size_t)e << 20) + (size_t)d0 * DH + f0;
        #pragma unroll
        for (int i = 0; i < 4; i++) {
            const int row = i * 16 + r;
            const float4 v = *(const float4*)(src + (size_t)row * DH + c4);
            tile[row][c4]     = v.x;
            tile[row][c4 + 1] = v.y;
            tile[row][c4 + 2] = v.z;
            tile[row][c4 + 3] = v.w;
        }
        __syncthreads();
        u16* dst = wbt + ((size_t)e << 20) + (size_t)f0 * DH + d0;
        #pragma unroll
        for (int i = 0; i < 4; i++) {
            const int orow = i * 16 + r;          // f-index within tile
            ushort4 o;
            o.x = f2b(tile[c4][orow]);
            o.y = f2b(tile[c4 + 1][orow]);
            o.z = f2b(tile[c4 + 2][orow]);
            o.w = f2b(tile[c4 + 3][orow]);
            *(ushort4*)(dst + (size_t)orow * DH + c4) = o;
        }
        return;
    }

    // ------- router: logits + softmax + top4 + buckets, fused x->bf16 cast (4 tokens/block) -------
    const int tid = threadIdx.x;
    const int wv = tid >> 6, lane = tid & 63;
    const int t = (blockIdx.x - 2048) * 4 + wv;
    if (tid < NE) { lcnt[tid] = 0; lprob[tid] = 0.f; }
    __syncthreads();

    float a[NE] = {};
    {
        const float* xr = x + (size_t)t * DH;
        u16* xbr = xb + (size_t)t * DH;
        const float4* wg = (const float4*)Wg;   // row d -> wg[2d] (e0..3), wg[2d+1] (e4..7)
        #pragma unroll
        for (int it = 0; it < 4; it++) {
            const int d = it * 256 + lane * 4;
            const float4 v = *(const float4*)(xr + d);
            ushort4 o;
            o.x = f2b(v.x); o.y = f2b(v.y); o.z = f2b(v.z); o.w = f2b(v.w);
            *(ushort4*)(xbr + d) = o;
            const float4 w0l = wg[2 * (d + 0)], w0h = wg[2 * (d + 0) + 1];
            const float4 w1l = wg[2 * (d + 1)], w1h = wg[2 * (d + 1) + 1];
            const float4 w2l = wg[2 * (d + 2)], w2h = wg[2 * (d + 2) + 1];
            const float4 w3l = wg[2 * (d + 3)], w3h = wg[2 * (d + 3) + 1];
            a[0] += v.x * w0l.x + v.y * w1l.x + v.z * w2l.x + v.w * w3l.x;
            a[1] += v.x * w0l.y + v.y * w1l.y + v.z * w2l.y + v.w * w3l.y;
            a[2] += v.x * w0l.z + v.y * w1l.z + v.z * w2l.z + v.w * w3l.z;
            a[3] += v.x * w0l.w + v.y * w1l.w + v.z * w2l.w + v.w * w3l.w;
            a[4] += v.x * w0h.x + v.y * w1h.x + v.z * w2h.x + v.w * w3h.x;
            a[5] += v.x * w0h.y + v.y * w1h.y + v.z * w2h.y + v.w * w3h.y;
            a[6] += v.x * w0h.z + v.y * w1h.z + v.z * w2h.z + v.w * w3h.z;
            a[7] += v.x * w0h.w + v.y * w1h.w + v.z * w2h.w + v.w * w3h.w;
        }
    }
    #pragma unroll
    for (int e = 0; e < NE; e++) {
        float v = a[e];
        #pragma unroll
        for (int off = 32; off > 0; off >>= 1) v += __shfl_down(v, off);
        a[e] = v;
    }

    int idx4[TK]; float w4[TK]; int off4[TK];
    if (lane == 0) {
        float logits[NE], probs[NE];
        float mx = -1e30f;
        #pragma unroll
        for (int e = 0; e < NE; e++) { logits[e] = a[e] + bg[e]; mx = fmaxf(mx, logits[e]); }
        float Z = 0.f;
        #pragma unroll
        for (int e = 0; e < NE; e++) { probs[e] = expf(logits[e] - mx); Z += probs[e]; }
        const float rZ = 1.f / Z;
        #pragma unroll
        for (int e = 0; e < NE; e++) probs[e] *= rZ;

        float rem2[NE];
        #pragma unroll
        for (int e = 0; e < NE; e++) rem2[e] = probs[e];
        float s4 = 0.f;
        #pragma unroll
        for (int k = 0; k < TK; k++) {   // strict > scan from 0 == jax tie-break (lowest idx)
            int best = 0; float bv = rem2[0];
            #pragma unroll
            for (int e = 1; e < NE; e++) if (rem2[e] > bv) { bv = rem2[e]; best = e; }
            idx4[k] = best; w4[k] = bv; s4 += bv; rem2[best] = -1e30f;
        }
        const float rs = 1.f / (s4 + 1e-6f);
        #pragma unroll
        for (int k = 0; k < TK; k++) {
            w4[k] *= rs;
            tk_e[t * TK + k] = idx4[k];
            tk_w[t * TK + k] = w4[k];
            off4[k] = atomicAdd(&lcnt[idx4[k]], 1);
        }
        #pragma unroll
        for (int e = 0; e < NE; e++) atomicAdd(&lprob[e], probs[e]);
    }
    __syncthreads();
    if (tid < NE) {
        gbase[tid] = atomicAdd(&cnt[tid], lcnt[tid]);
        atomicAdd(&probsum[tid], lprob[tid]);
    }
    __syncthreads();
    if (lane == 0) {
        #pragma unroll
        for (int k = 0; k < TK; k++) {
            const int e = idx4[k];
            const int slot = gbase[e] + off4[k];
            bucket_tok[e * T_TOK + slot] = (t << 2) | k;
            bucket_w[e * T_TOK + slot]   = w4[k];
        }
    }
}

// ---------------- grouped gather GEMM, 128x256 / BK=64 / 8-wave / 2-phase, 3-deep pipeline ----------------
// R5 = R4 with the compile fix (glds16 offset folded into pointer; builtin offset arg must be literal).
//  - BM=128, BN=256, 8 waves 2Mx4N, per-wave 64x64 (acc[4][4]); 16-MFMA phase clusters.
//  - LDS 145KB: As[3][128*64], Bs[3][256*64] u16, 3-deep; tile k lives in buf k%3.
//  - T2 XOR swizzle identical to R2/R3 (verified 0-conflict).
//  - Stage ledger (per wave, 2 glds each): BH(k+2) @P1(k); A(k+3),BL(k+3) @P2(k) -> ~4 phases flight.
//    Derived waits: end-P1(k): vmcnt(12) [k<=13], 6 [k=14], 0 [k=15];
//                   end-P2(k): vmcnt(12) [k<=12], 8 [k=13], 2 [k=14]. Never drained mid-loop.
//  - WAR: A/BL rows of buf k%3 die at P1(k)'s closing barrier (restaged P2(k));
//         BH rows die at P2(k-1)'s closing barrier (restaged P1(k)).
//  - Grid: expert-per-XCD; ~1040 tiles over 256 blocks: makespan 5/4.06 = 1.23x (was 1.45x).
__global__ __launch_bounds__(512, 1) void moe_gemm_kernel(
    const u16* __restrict__ xb, const u16* __restrict__ wbt,
    const int* __restrict__ bucket_tok, const float* __restrict__ bucket_w,
    const int* __restrict__ cnt, u16* __restrict__ y)
{
    __shared__ u16 As[3][128 * 64];   // 48 KB
    __shared__ u16 Bs[3][256 * 64];   // 96 KB
    __shared__ int   s_tok[128];
    __shared__ float s_w[128];

    const int tid  = threadIdx.x;
    const int lane = tid & 63;
    const int wid  = tid >> 6;            // 0..7
    const int wr   = wid >> 2;            // 0..1 (M)
    const int wc   = wid & 3;             // 0..3 (N)
    const int fr   = lane & 15;
    const int fq   = (lane >> 4) * 8;
    const int swz  = (fr & 7) << 3;       // u16-index XOR for frag reads
    const int gsw  = ((lane & 7) ^ (lane >> 3)) * 8;  // pre-swizzled global u16 col for staging
    const int crow = lane >> 3;           // row within 8-row chunk

    // chunk = 8 rows x 128B, one glds16. A: 16 chunks (2/wave). B: 32 chunks; BL = chunks c with
    // (c&7)<4 (rows [0,32) mod 64, feeding nj=0,1), BH = +4. Wave w owns slots i=2w,2w+1.
    const int i0  = 2 * wid, i1 = 2 * wid + 1;
    const int blC0 = (i0 >> 2) * 8 + (i0 & 3);
    const int blC1 = (i1 >> 2) * 8 + (i1 & 3);
    const int bhC0 = blC0 + 4, bhC1 = blC1 + 4;

    const int e  = blockIdx.x & 7;         // expert-per-XCD
    const int cc = blockIdx.x >> 3;        // 0..31 within XCD
    const int M  = cnt[e];

    for (int j = 0; j < 8; ++j) {
        const int idx = j * 32 + cc;       // tile index within expert
        const int mb = idx >> 2;
        const int nb = idx & 3;
        const int m0 = mb << 7;
        if (m0 >= M) continue;
        const int n0 = nb << 8;

        __syncthreads();                   // s_tok/s_w + LDS reuse across tiles (drains vmcnt too)
        if (tid < 128) {
            const int slot = m0 + tid;
            if (slot < M) {
                s_tok[tid] = bucket_tok[e * T_TOK + slot];
                s_w[tid]   = bucket_w[e * T_TOK + slot];
            } else { s_tok[tid] = -1; s_w[tid] = 0.f; }
        }
        __syncthreads();

        const int rA0 = i0 * 8 + crow, rA1 = i1 * 8 + crow;
        const int tA0 = s_tok[rA0], tA1 = s_tok[rA1];
        const u16* gA0 = xb + (size_t)(tA0 >= 0 ? (tA0 >> 2) : 0) * DH + gsw;
        const u16* gA1 = xb + (size_t)(tA1 >= 0 ? (tA1 >> 2) : 0) * DH + gsw;
        const u16* wbe = wbt + ((size_t)e << 20);
        const u16* gBL0 = wbe + (size_t)(n0 + blC0 * 8 + crow) * DH + gsw;
        const u16* gBL1 = wbe + (size_t)(n0 + blC1 * 8 + crow) * DH + gsw;
        const u16* gBH0 = wbe + (size_t)(n0 + bhC0 * 8 + crow) * DH + gsw;
        const u16* gBH1 = wbe + (size_t)(n0 + bhC1 * 8 + crow) * DH + gsw;

        f32x4 acc[4][4] = {};

        // kt*64 u16 = kt*128 B = K-tile byte offset, folded into the pointer (literal-offset fix)
        #define STG_A(kt)  do { glds16(gA0  + (kt) * 64, &As[(kt) % 3][i0   * 512]); \
                                glds16(gA1  + (kt) * 64, &As[(kt) % 3][i1   * 512]); } while (0)
        #define STG_BL(kt) do { glds16(gBL0 + (kt) * 64, &Bs[(kt) % 3][blC0 * 512]); \
                                glds16(gBL1 + (kt) * 64, &Bs[(kt) % 3][blC1 * 512]); } while (0)
        #define STG_BH(kt) do { glds16(gBH0 + (kt) * 64, &Bs[(kt) % 3][bhC0 * 512]); \
                                glds16(gBH1 + (kt) * 64, &Bs[(kt) % 3][bhC1 * 512]); } while (0)

        // prologue (matches steady-state ledger): A0,BL0 | BH0 | A1,BL1 | BH1 | A2,BL2
        STG_A(0); STG_BL(0); STG_BH(0); STG_A(1); STG_BL(1); STG_BH(1); STG_A(2); STG_BL(2);
        WAITVM(12);            // 16 in flight - keep 12 -> A0,BL0 retired
        SBAR();

        const int arow = (wr * 64 + fr) * 64;     // u16 base of this lane's A frag rows
        const int brow = (wc * 64 + fr) * 64;
        const int c0 = fq ^ swz;                  // k-half 0 column (u16)
        const int c1 = (32 + fq) ^ swz;           // k-half 1 column

        #pragma unroll
        for (int kt = 0; kt < 16; ++kt) {
            const u16* Ap = &As[kt % 3][0];
            const u16* Bp = &Bs[kt % 3][0];
            bf16x8 af[4][2], bl[2][2], bh[2][2];

            // ---- P1: read af(8)+bfL(4); stage BH(kt+2) -> buf (kt+2)%3; MFMA mi x nj0-1 ----
            #pragma unroll
            for (int mi = 0; mi < 4; mi++) {
                af[mi][0] = *(const bf16x8*)&Ap[arow + mi * 1024 + c0];
                af[mi][1] = *(const bf16x8*)&Ap[arow + mi * 1024 + c1];
            }
            #pragma unroll
            for (int nj = 0; nj < 2; nj++) {
                bl[nj][0] = *(const bf16x8*)&Bp[brow + nj * 1024 + c0];
                bl[nj][1] = *(const bf16x8*)&Bp[brow + nj * 1024 + c1];
            }
            if (kt <= 13) STG_BH(kt + 2);          // BH rows of (kt+2)%3 died at P2(kt-1)
            asm volatile("s_waitcnt lgkmcnt(8)" ::: "memory");   // 12-read-phase hint (template)
            SBAR(); WAITLGKM0();
            __builtin_amdgcn_s_setprio(1);
            #pragma unroll
            for (int mi = 0; mi < 4; mi++)
                #pragma unroll
                for (int nj = 0; nj < 2; nj++) {
                    acc[mi][nj] = __builtin_amdgcn_mfma_f32_16x16x32_bf16(af[mi][0], bl[nj][0], acc[mi][nj], 0, 0, 0);
                    acc[mi][nj] = __builtin_amdgcn_mfma_f32_16x16x32_bf16(af[mi][1], bl[nj][1], acc[mi][nj], 0, 0, 0);
                }
            __builtin_amdgcn_s_setprio(0);
            if (kt <= 13)      WAITVM(12);        // protect BH(kt) for P2's reads
            else if (kt == 14) WAITVM(6);
            else               WAITVM(0);
            SBAR();                                // A/BL rows of buf kt%3 now dead (all waves)

            // ---- P2: read bfH(4); stage A(kt+3),BL(kt+3) -> buf (kt+3)%3 (= kt%3); MFMA mi x nj2-3 ----
            #pragma unroll
            for (int nj = 0; nj < 2; nj++) {
                bh[nj][0] = *(const bf16x8*)&Bp[brow + (nj + 2) * 1024 + c0];
                bh[nj][1] = *(const bf16x8*)&Bp[brow + (nj + 2) * 1024 + c1];
            }
            if (kt <= 12) { STG_A(kt + 3); STG_BL(kt + 3); }
            SBAR(); WAITLGKM0();
            __builtin_amdgcn_s_setprio(1);
            #pragma unroll
            for (int mi = 0; mi < 4; mi++)
                #pragma unroll
                for (int nj = 0; nj < 2; nj++) {
                    acc[mi][nj + 2] = __builtin_amdgcn_mfma_f32_16x16x32_bf16(af[mi][0], bh[nj][0], acc[mi][nj + 2], 0, 0, 0);
                    acc[mi][nj + 2] = __builtin_amdgcn_mfma_f32_16x16x32_bf16(af[mi][1], bh[nj][1], acc[mi][nj + 2], 0, 0, 0);
                }
            __builtin_amdgcn_s_setprio(0);
            if (kt <= 12)      WAITVM(12);        // protect A/BL(kt+1) for next P1's reads
            else if (kt == 13) WAITVM(8);
            else if (kt == 14) WAITVM(2);
            SBAR();                                // BH rows of buf kt%3 now dead
        }
        #undef STG_A
        #undef STG_BL
        #undef STG_BH

        // C/D layout: col = lane&15, row = (lane>>4)*4 + r
        const int cl = lane & 15;
        const int rb = (lane >> 4) * 4;
        #pragma unroll
        for (int mi = 0; mi < 4; mi++) {
            #pragma unroll
            for (int r = 0; r < 4; r++) {
                const int srow = wr * 64 + mi * 16 + rb + r;
                const int tok = s_tok[srow];
                if (tok < 0) continue;
                const float w = s_w[srow];
                u16* yr = y + (size_t)tok * DH + (n0 + wc * 64 + cl);
                #pragma unroll
                for (int nj = 0; nj < 4; nj++)
                    yr[nj * 16] = f2b(acc[mi][nj][r] * w);
            }
        }
    }
}

// ---------------- combine: out[t] = sum_k y[t*4+k] + sum_k w_k*b[e_k]; block 0 does aux ----------------
__global__ __launch_bounds__(256) void combine_kernel(
    const u16* __restrict__ y, const int* __restrict__ tk_e, const float* __restrict__ tk_w,
    const float* __restrict__ bexp,
    const int* __restrict__ cnt, const float* __restrict__ probsum,
    float* __restrict__ out, float* __restrict__ out_aux)
{
    const int t = blockIdx.x;
    const int c = threadIdx.x * 4;
    if (t == 0 && threadIdx.x == 0) {
        float s = 0.f;
        for (int e = 0; e < NE; e++) s += (float)cnt[e] * probsum[e];
        out_aux[0] = s * (float)NE / ((float)T_TOK * (float)T_TOK);
    }
    float o0 = 0.f, o1 = 0.f, o2 = 0.f, o3 = 0.f;
    #pragma unroll
    for (int k = 0; k < TK; k++) {
        const int e   = tk_e[t * TK + k];
        const float w = tk_w[t * TK + k];
        const ushort4 yv = *(const ushort4*)(y + ((size_t)(t * TK + k)) * DH + c);
        const float4  bv = *(const float4*)(bexp + (size_t)e * DH + c);
        o0 += b2f(yv.x) + w * bv.x;
        o1 += b2f(yv.y) + w * bv.y;
        o2 += b2f(yv.z) + w * bv.z;
        o3 += b2f(yv.w) + w * bv.w;
    }
    float4 ov = {o0, o1, o2, o3};
    *(float4*)(out + (size_t)t * DH + c) = ov;
}

extern "C" void kernel_launch(void* const* d_in, const int* in_sizes, int n_in,
                              void* d_out, int out_size, void* d_ws, size_t ws_size,
                              hipStream_t stream)
{
    const float* x  = (const float*)d_in[0];
    const float* Wg = (const float*)d_in[1];
    const float* bg = (const float*)d_in[2];
    const float* W  = (const float*)d_in[3];
    const float* b  = (const float*)d_in[4];
    float* out = (float*)d_out;

    char* ws = (char*)d_ws;
    u16*   xb         = (u16*)(ws);                    // 16,777,216 B
    u16*   wbt        = (u16*)(ws + 16777216);         // 16,777,216 B
    u16*   y          = (u16*)(ws + 33554432);         // 67,108,864 B
    int*   bucket_tok = (int*)(ws + 100663296);        //    262,144 B
    float* bucket_w   = (float*)(ws + 100925440);      //    262,144 B
    int*   tk_e       = (int*)(ws + 101187584);        //    131,072 B
    float* tk_w       = (float*)(ws + 101318656);      //    131,072 B
    int*   cnt        = (int*)(ws + 101449728);        //         32 B
    float* probsum    = (float*)(ws + 101449760);      //         32 B

    hipMemsetAsync(cnt, 0, 64, stream);  // cnt + probsum

    prep_kernel<<<4096, 256, 0, stream>>>(W, wbt, x, Wg, bg, xb,
                                          bucket_tok, bucket_w, tk_e, tk_w, cnt, probsum);
    moe_gemm_kernel<<<dim3(256), 512, 0, stream>>>(xb, wbt, bucket_tok, bucket_w, cnt, y);
    combine_kernel<<<8192, 256, 0, stream>>>(y, tk_e, tk_w, b, cnt, probsum, out, out + (size_t)T_TOK * DH);
}